// Round 2
// baseline (1665.768 us; speedup 1.0000x reference)
//
#include <hip/hip_runtime.h>
#include <stdint.h>

constexpr int FEATC = 1024;
constexpr int H0 = 128;

static inline int ceil_div(int a, int b){ return (a + b - 1) / b; }

// ---------------- CSR build ----------------

__global__ __launch_bounds__(256) void init_kernel(int* __restrict__ cnt, int* __restrict__ fill, int n) {
    int i = blockIdx.x * 256 + threadIdx.x;
    if (i < n) { cnt[i] = 0; fill[i] = 0; }
}

__global__ __launch_bounds__(256) void count_kernel(const int* __restrict__ ei, int* __restrict__ cnt, int E) {
    int e = blockIdx.x * 256 + threadIdx.x;
    if (e < E) atomicAdd(&cnt[ei[E + e]], 1);   // dst row of edge_index
}

__global__ __launch_bounds__(256) void dinv_kernel(const int* __restrict__ cnt, float* __restrict__ dinv, int n) {
    int i = blockIdx.x * 256 + threadIdx.x;
    if (i < n) dinv[i] = rsqrtf((float)(cnt[i] + 1));   // +1 self loop; deg >= 1 always
}

// single-block exclusive scan of cnt[0..n) -> rowptr[0..n]
__global__ __launch_bounds__(1024) void scan_kernel(const int* __restrict__ cnt, int* __restrict__ rowptr, int n) {
    __shared__ int wsum[16];
    __shared__ int carry_s;
    const int tid = threadIdx.x;
    const int lane = tid & 63, wid = tid >> 6;
    if (tid == 0) carry_s = 0;
    __syncthreads();
    for (int base = 0; base < n; base += 1024) {
        int idx = base + tid;
        int v = (idx < n) ? cnt[idx] : 0;
        int s = v;
        #pragma unroll
        for (int off = 1; off < 64; off <<= 1) {
            int t = __shfl_up(s, off, 64);
            if (lane >= off) s += t;
        }
        if (lane == 63) wsum[wid] = s;
        __syncthreads();
        if (wid == 0) {
            int ws = (lane < 16) ? wsum[lane] : 0;
            #pragma unroll
            for (int off = 1; off < 16; off <<= 1) {
                int t = __shfl_up(ws, off, 64);
                if (lane >= off) ws += t;
            }
            if (lane < 16) wsum[lane] = ws;
        }
        __syncthreads();
        int carry = carry_s;
        if (idx < n) rowptr[idx] = carry + (wid ? wsum[wid - 1] : 0) + s - v;
        __syncthreads();
        if (tid == 1023) carry_s = carry + wsum[15];
        __syncthreads();
    }
    if (tid == 0) rowptr[n] = carry_s;
}

__global__ __launch_bounds__(256) void fill_kernel(const int* __restrict__ ei, const int* __restrict__ rowptr,
                                                   int* __restrict__ fill, int* __restrict__ adj, int E) {
    int e = blockIdx.x * 256 + threadIdx.x;
    if (e < E) {
        int d = ei[E + e];
        int pos = rowptr[d] + atomicAdd(&fill[d], 1);
        adj[pos] = ei[e];
    }
}

// ---------------- fp32 tiled GEMM:  C[n][BN] = A[n][K] @ W[K][BN] (+bias) ----------------
// BM=64, BK=32, 256 threads; TM=BN/16, TN=4.
template<int BN, bool BIAS, bool SPLIT>
__global__ __launch_bounds__(256) void gemm_kernel(
    const float* __restrict__ A,
    const float* __restrict__ Wa, const float* __restrict__ Wb2,
    const float* __restrict__ ba, const float* __restrict__ bb2,
    float* __restrict__ C, int n, int K)
{
    constexpr int BM = 64, BK = 32;
    constexpr int TN = 4;
    constexpr int TM = BN / 16;        // 8 (BN=128) or 4 (BN=64)
    constexpr int CT = BN / TN;        // thread-columns: 32 or 16
    __shared__ float As[BK][BM + 4];   // row stride 68 floats = 272 B (16B-aligned)
    __shared__ float Bs[BK][BN];

    const int tid = threadIdx.x;
    const int row0 = blockIdx.x * BM;
    const float* W    = (SPLIT && row0 >= 1024) ? Wb2 : Wa;
    const float* bias = (SPLIT && row0 >= 1024) ? bb2 : ba;
    const int tc = tid % CT;
    const int tr = tid / CT;

    float acc[TM][TN];
    #pragma unroll
    for (int i = 0; i < TM; ++i)
        #pragma unroll
        for (int j = 0; j < TN; ++j) acc[i][j] = 0.f;

    for (int k0 = 0; k0 < K; k0 += BK) {
        // A tile: 64x32 floats = 512 float4 -> 2 per thread; store transposed
        #pragma unroll
        for (int i = 0; i < 2; ++i) {
            int q = tid + i * 256;
            int r = q >> 3;            // / (BK/4)
            int cq = q & 7;
            int grow = row0 + r;
            float4 v = make_float4(0.f, 0.f, 0.f, 0.f);
            if (grow < n) v = *reinterpret_cast<const float4*>(A + (size_t)grow * K + k0 + cq * 4);
            As[cq * 4 + 0][r] = v.x; As[cq * 4 + 1][r] = v.y;
            As[cq * 4 + 2][r] = v.z; As[cq * 4 + 3][r] = v.w;
        }
        // B tile: 32xBN floats -> BN/32 float4 per thread
        #pragma unroll
        for (int i = 0; i < BN / 32; ++i) {
            int q = tid + i * 256;
            int r = q / (BN / 4);
            int cq = q % (BN / 4);
            *reinterpret_cast<float4*>(&Bs[r][cq * 4]) =
                *reinterpret_cast<const float4*>(W + (size_t)(k0 + r) * BN + cq * 4);
        }
        __syncthreads();
        #pragma unroll
        for (int k = 0; k < BK; ++k) {
            float a[TM], b[TN];
            #pragma unroll
            for (int i = 0; i < TM; i += 4)
                *reinterpret_cast<float4*>(&a[i]) = *reinterpret_cast<const float4*>(&As[k][tr * TM + i]);
            *reinterpret_cast<float4*>(&b[0]) = *reinterpret_cast<const float4*>(&Bs[k][tc * TN]);
            #pragma unroll
            for (int i = 0; i < TM; ++i)
                #pragma unroll
                for (int j = 0; j < TN; ++j)
                    acc[i][j] = fmaf(a[i], b[j], acc[i][j]);
        }
        __syncthreads();
    }
    #pragma unroll
    for (int i = 0; i < TM; ++i) {
        int grow = row0 + tr * TM + i;
        if (grow < n) {
            float4 v = make_float4(acc[i][0], acc[i][1], acc[i][2], acc[i][3]);
            if (BIAS) {
                v.x += bias[tc * TN + 0]; v.y += bias[tc * TN + 1];
                v.z += bias[tc * TN + 2]; v.w += bias[tc * TN + 3];
            }
            *reinterpret_cast<float4*>(C + (size_t)grow * BN + tc * TN) = v;
        }
    }
}

// ---------------- aggregation: out[i] = dinv[i]*sum_e dinv[s]*hw[s] + dinv[i]^2*hw[i] + b ----------------
// one wave (64 lanes) per node
template<int COLS, bool RELU>
__global__ __launch_bounds__(256) void agg_kernel(
    const float* __restrict__ hw, const float* __restrict__ dinv,
    const int* __restrict__ rowptr, const int* __restrict__ adj,
    const float* __restrict__ bias, float* __restrict__ out, int n)
{
    const int node = (int)((blockIdx.x * (size_t)blockDim.x + threadIdx.x) >> 6);
    const int lane = threadIdx.x & 63;
    if (node >= n) return;
    const int beg = rowptr[node], end = rowptr[node + 1];
    const float di = dinv[node];

    if (COLS == 128) {
        float acc0 = 0.f, acc1 = 0.f;
        int e = beg;
        for (; e + 1 < end; e += 2) {
            int s0 = adj[e], s1 = adj[e + 1];
            float w0 = dinv[s0], w1 = dinv[s1];
            float2 r0 = *reinterpret_cast<const float2*>(hw + (size_t)s0 * 128 + 2 * lane);
            float2 r1 = *reinterpret_cast<const float2*>(hw + (size_t)s1 * 128 + 2 * lane);
            acc0 += w0 * r0.x; acc1 += w0 * r0.y;
            acc0 += w1 * r1.x; acc1 += w1 * r1.y;
        }
        if (e < end) {
            int s0 = adj[e];
            float w0 = dinv[s0];
            float2 r0 = *reinterpret_cast<const float2*>(hw + (size_t)s0 * 128 + 2 * lane);
            acc0 += w0 * r0.x; acc1 += w0 * r0.y;
        }
        float2 self = *reinterpret_cast<const float2*>(hw + (size_t)node * 128 + 2 * lane);
        float v0 = di * acc0 + di * di * self.x + bias[2 * lane + 0];
        float v1 = di * acc1 + di * di * self.y + bias[2 * lane + 1];
        if (RELU) { v0 = fmaxf(v0, 0.f); v1 = fmaxf(v1, 0.f); }
        *reinterpret_cast<float2*>(out + (size_t)node * 128 + 2 * lane) = make_float2(v0, v1);
    } else {
        float acc0 = 0.f;
        int e = beg;
        for (; e + 1 < end; e += 2) {
            int s0 = adj[e], s1 = adj[e + 1];
            float w0 = dinv[s0], w1 = dinv[s1];
            float r0 = hw[(size_t)s0 * COLS + lane];
            float r1 = hw[(size_t)s1 * COLS + lane];
            acc0 += w0 * r0 + w1 * r1;
        }
        if (e < end) {
            int s0 = adj[e];
            acc0 += dinv[s0] * hw[(size_t)s0 * COLS + lane];
        }
        float self = hw[(size_t)node * COLS + lane];
        float v0 = di * acc0 + di * di * self + bias[lane];
        if (RELU) v0 = fmaxf(v0, 0.f);
        out[(size_t)node * COLS + lane] = v0;
    }
}

// ---------------- launcher ----------------

extern "C" void kernel_launch(void* const* d_in, const int* in_sizes, int n_in,
                              void* d_out, int out_size, void* d_ws, size_t ws_size,
                              hipStream_t stream) {
    const float* x  = (const float*)d_in[0];
    const int*   ei = (const int*)  d_in[1];
    const float* Wu = (const float*)d_in[2];
    const float* bu = (const float*)d_in[3];
    const float* Wb = (const float*)d_in[4];
    const float* bb = (const float*)d_in[5];
    const float* W1 = (const float*)d_in[6];
    const float* b1 = (const float*)d_in[7];
    const float* W2 = (const float*)d_in[8];
    const float* b2 = (const float*)d_in[9];
    const float* W3 = (const float*)d_in[10];
    const float* b3 = (const float*)d_in[11];
    float* out = (float*)d_out;

    const int N_ = in_sizes[0] / FEATC;   // 101024
    const int E_ = in_sizes[1] / 2;       // 2,000,000

    size_t off = 0;
    auto carve = [&](size_t bytes) -> void* {
        void* p = (char*)d_ws + off;
        off += (bytes + 255) & ~(size_t)255;
        return p;
    };
    float* buf0   = (float*)carve((size_t)N_ * H0 * sizeof(float));
    float* buf1   = (float*)carve((size_t)N_ * H0 * sizeof(float));
    float* dinv   = (float*)carve((size_t)N_ * sizeof(float));
    int*   cnt    = (int*)  carve((size_t)N_ * sizeof(int));
    int*   fillc  = (int*)  carve((size_t)N_ * sizeof(int));
    int*   rowptr = (int*)  carve(((size_t)N_ + 1) * sizeof(int));
    int*   adj    = (int*)  carve((size_t)E_ * sizeof(int));

    // CSR + norm build
    init_kernel<<<ceil_div(N_, 256), 256, 0, stream>>>(cnt, fillc, N_);
    count_kernel<<<ceil_div(E_, 256), 256, 0, stream>>>(ei, cnt, E_);
    dinv_kernel<<<ceil_div(N_, 256), 256, 0, stream>>>(cnt, dinv, N_);
    scan_kernel<<<1, 1024, 0, stream>>>(cnt, rowptr, N_);
    fill_kernel<<<ceil_div(E_, 256), 256, 0, stream>>>(ei, rowptr, fillc, adj, E_);

    const int gemm_grid = ceil_div(N_, 64);
    const int agg_grid  = ceil_div(N_, 4);   // 4 waves/block, wave per node

    // h0 = proj(x)  [N,128]
    gemm_kernel<128, true, true><<<gemm_grid, 256, 0, stream>>>(x, Wu, Wb, bu, bb, buf0, N_, FEATC);
    // layer 1
    gemm_kernel<128, false, false><<<gemm_grid, 256, 0, stream>>>(buf0, W1, W1, nullptr, nullptr, buf1, N_, H0);
    agg_kernel<128, true><<<agg_grid, 256, 0, stream>>>(buf1, dinv, rowptr, adj, b1, buf0, N_);
    // layer 2
    gemm_kernel<128, false, false><<<gemm_grid, 256, 0, stream>>>(buf0, W2, W2, nullptr, nullptr, buf1, N_, H0);
    agg_kernel<128, true><<<agg_grid, 256, 0, stream>>>(buf1, dinv, rowptr, adj, b2, buf0, N_);
    // layer 3 (no relu), write d_out
    gemm_kernel<64, false, false><<<gemm_grid, 256, 0, stream>>>(buf0, W3, W3, nullptr, nullptr, buf1, N_, H0);
    agg_kernel<64, false><<<agg_grid, 256, 0, stream>>>(buf1, dinv, rowptr, adj, b3, out, N_);
}

// Round 3
// 1467.362 us; speedup vs baseline: 1.1352x; 1.1352x over previous
//
#include <hip/hip_runtime.h>
#include <stdint.h>

typedef __attribute__((ext_vector_type(8))) short bf16x8;
typedef __attribute__((ext_vector_type(4))) float f32x4;

constexpr int FEATC = 1024;
constexpr int H0 = 128;

static inline int ceil_div(int a, int b){ return (a + b - 1) / b; }

__device__ inline ushort f2bf_rne(float f) {
    uint u = __float_as_uint(f);
    uint r = (u + 0x7FFFu + ((u >> 16) & 1u)) >> 16;
    return (ushort)r;
}
__device__ inline float bf2f(ushort h) { return __uint_as_float(((uint)h) << 16); }
__device__ inline uint pack2(ushort a, ushort b) { return (uint)a | ((uint)b << 16); }

// ---------------- CSR build ----------------

__global__ __launch_bounds__(256) void init_kernel(int* __restrict__ cnt, int* __restrict__ fill, int n) {
    int i = blockIdx.x * 256 + threadIdx.x;
    if (i < n) { cnt[i] = 0; fill[i] = 0; }
}

__global__ __launch_bounds__(256) void count_kernel(const int* __restrict__ ei, int* __restrict__ cnt, int E) {
    int e = blockIdx.x * 256 + threadIdx.x;
    if (e < E) atomicAdd(&cnt[ei[E + e]], 1);   // dst row of edge_index
}

__global__ __launch_bounds__(256) void dinv_kernel(const int* __restrict__ cnt, float* __restrict__ dinv, int n) {
    int i = blockIdx.x * 256 + threadIdx.x;
    if (i < n) dinv[i] = rsqrtf((float)(cnt[i] + 1));   // +1 self loop
}

// single-block exclusive scan of cnt[0..n) -> rowptr[0..n]
__global__ __launch_bounds__(1024) void scan_kernel(const int* __restrict__ cnt, int* __restrict__ rowptr, int n) {
    __shared__ int wsum[16];
    __shared__ int carry_s;
    const int tid = threadIdx.x;
    const int lane = tid & 63, wid = tid >> 6;
    if (tid == 0) carry_s = 0;
    __syncthreads();
    for (int base = 0; base < n; base += 1024) {
        int idx = base + tid;
        int v = (idx < n) ? cnt[idx] : 0;
        int s = v;
        #pragma unroll
        for (int off = 1; off < 64; off <<= 1) {
            int t = __shfl_up(s, off, 64);
            if (lane >= off) s += t;
        }
        if (lane == 63) wsum[wid] = s;
        __syncthreads();
        if (wid == 0) {
            int ws = (lane < 16) ? wsum[lane] : 0;
            #pragma unroll
            for (int off = 1; off < 16; off <<= 1) {
                int t = __shfl_up(ws, off, 64);
                if (lane >= off) ws += t;
            }
            if (lane < 16) wsum[lane] = ws;
        }
        __syncthreads();
        int carry = carry_s;
        if (idx < n) rowptr[idx] = carry + (wid ? wsum[wid - 1] : 0) + s - v;
        __syncthreads();
        if (tid == 1023) carry_s = carry + wsum[15];
        __syncthreads();
    }
    if (tid == 0) rowptr[n] = carry_s;
}

__global__ __launch_bounds__(256) void fill_kernel(const int* __restrict__ ei, const int* __restrict__ rowptr,
                                                   int* __restrict__ fill, int* __restrict__ adj, int E) {
    int e = blockIdx.x * 256 + threadIdx.x;
    if (e < E) {
        int d = ei[E + e];
        int pos = rowptr[d] + atomicAdd(&fill[d], 1);
        adj[pos] = ei[e];
    }
}

// ---------------- weight pack: W [K][N] fp32 -> Wt_hi/Wt_lo [N][K] bf16 ----------------
__global__ __launch_bounds__(256) void pack_w_kernel(const float* __restrict__ W, ushort* __restrict__ hi,
                                                     ushort* __restrict__ lo, int K, int N) {
    int o = blockIdx.x * 256 + threadIdx.x;
    if (o >= K * N) return;
    int nn = o / K, kk = o - nn * K;
    float f = W[(size_t)kk * N + nn];
    ushort h = f2bf_rne(f);
    float fl = f - bf2f(h);
    hi[o] = h;
    lo[o] = f2bf_rne(fl);
}

// ---------------- bf16x3-split MFMA GEMM: C[n][NCOLS] = A[n][K] @ W[K][NCOLS] (+bias) ----------------
// BM=128, BK=64. Waves: 4 (m) x NCOLS/64 (n). A converted fp32->bf16 hi/lo on the fly.
// LDS rows are 128B; T2 XOR swizzle byte^=((row&7)<<4) on both write and read.
template<int NCOLS, bool BIAS, bool SPLIT>
__global__ __launch_bounds__(NCOLS == 128 ? 512 : 256) void mfma_gemm_kernel(
    const float* __restrict__ A, int lda, int K, int n,
    const ushort* __restrict__ WtHiA, const ushort* __restrict__ WtLoA,
    const ushort* __restrict__ WtHiB, const ushort* __restrict__ WtLoB,
    const float* __restrict__ biasA, const float* __restrict__ biasB,
    float* __restrict__ C)
{
    constexpr int BM = 128, BK = 64;
    constexpr int WN = NCOLS / 64;            // 2 or 1
    constexpr int THREADS = 4 * WN * 64;      // 512 or 256
    constexpr int ASTEPS = (BM * BK / 4) / THREADS;   // 4 or 8
    constexpr int BSTEPS = (NCOLS * BK / 8) / THREADS; // 2 or 2

    __shared__ alignas(16) ushort Ahi[BM * BK], Alo[BM * BK];
    __shared__ alignas(16) ushort Bhi[NCOLS * BK], Blo[NCOLS * BK];

    const int tid = threadIdx.x;
    const int row0 = blockIdx.x * BM;
    const ushort* WtHi = (SPLIT && row0 >= 1024) ? WtHiB : WtHiA;
    const ushort* WtLo = (SPLIT && row0 >= 1024) ? WtLoB : WtLoA;
    const float*  bias = (SPLIT && row0 >= 1024) ? biasB : biasA;

    const int wave = tid >> 6, lane = tid & 63;
    const int wn = wave % WN, wm = wave / WN;
    const int r15 = lane & 15, g = lane >> 4;

    f32x4 acc[2][4];
    #pragma unroll
    for (int i = 0; i < 2; ++i)
        #pragma unroll
        for (int j = 0; j < 4; ++j) acc[i][j] = (f32x4){0.f, 0.f, 0.f, 0.f};

    for (int k0 = 0; k0 < K; k0 += BK) {
        __syncthreads();
        // stage A: BM x BK fp32 -> hi/lo bf16 LDS
        #pragma unroll
        for (int ii = 0; ii < ASTEPS; ++ii) {
            int chunk = tid + ii * THREADS;
            int r = chunk >> 4, c = chunk & 15;       // r: row 0..127, c: float4 idx 0..15
            int grow = row0 + r;
            float4 v = make_float4(0.f, 0.f, 0.f, 0.f);
            if (grow < n) v = *reinterpret_cast<const float4*>(A + (size_t)grow * lda + k0 + c * 4);
            ushort h0 = f2bf_rne(v.x), h1 = f2bf_rne(v.y), h2 = f2bf_rne(v.z), h3 = f2bf_rne(v.w);
            ushort l0 = f2bf_rne(v.x - bf2f(h0)), l1 = f2bf_rne(v.y - bf2f(h1));
            ushort l2 = f2bf_rne(v.z - bf2f(h2)), l3 = f2bf_rne(v.w - bf2f(h3));
            int bo = r * 128 + c * 8;
            int sw = bo ^ (((bo >> 7) & 7) << 4);
            *reinterpret_cast<uint2*>((char*)Ahi + sw) = make_uint2(pack2(h0, h1), pack2(h2, h3));
            *reinterpret_cast<uint2*>((char*)Alo + sw) = make_uint2(pack2(l0, l1), pack2(l2, l3));
        }
        // stage B: NCOLS x BK bf16 hi/lo from packed Wt [N][K]
        #pragma unroll
        for (int ii = 0; ii < BSTEPS; ++ii) {
            int chunk = tid + ii * THREADS;
            int r = chunk >> 3, gg = chunk & 7;       // r: col-row 0..NCOLS-1, gg: 16B granule
            bf16x8 hv = *reinterpret_cast<const bf16x8*>(WtHi + (size_t)r * K + k0 + gg * 8);
            bf16x8 lv = *reinterpret_cast<const bf16x8*>(WtLo + (size_t)r * K + k0 + gg * 8);
            int bo = r * 128 + gg * 16;
            int sw = bo ^ (((bo >> 7) & 7) << 4);
            *reinterpret_cast<bf16x8*>((char*)Bhi + sw) = hv;
            *reinterpret_cast<bf16x8*>((char*)Blo + sw) = lv;
        }
        __syncthreads();
        #pragma unroll
        for (int ks = 0; ks < 2; ++ks) {
            bf16x8 ah[2], al[2], bh[4], bl[4];
            #pragma unroll
            for (int mi = 0; mi < 2; ++mi) {
                int row = wm * 32 + mi * 16 + r15;
                int bo = row * 128 + ks * 64 + g * 16;
                int sw = bo ^ (((bo >> 7) & 7) << 4);
                ah[mi] = *reinterpret_cast<const bf16x8*>((const char*)Ahi + sw);
                al[mi] = *reinterpret_cast<const bf16x8*>((const char*)Alo + sw);
            }
            #pragma unroll
            for (int ni = 0; ni < 4; ++ni) {
                int row = wn * 64 + ni * 16 + r15;
                int bo = row * 128 + ks * 64 + g * 16;
                int sw = bo ^ (((bo >> 7) & 7) << 4);
                bh[ni] = *reinterpret_cast<const bf16x8*>((const char*)Bhi + sw);
                bl[ni] = *reinterpret_cast<const bf16x8*>((const char*)Blo + sw);
            }
            #pragma unroll
            for (int mi = 0; mi < 2; ++mi)
                #pragma unroll
                for (int ni = 0; ni < 4; ++ni) {
                    acc[mi][ni] = __builtin_amdgcn_mfma_f32_16x16x32_bf16(ah[mi], bh[ni], acc[mi][ni], 0, 0, 0);
                    acc[mi][ni] = __builtin_amdgcn_mfma_f32_16x16x32_bf16(ah[mi], bl[ni], acc[mi][ni], 0, 0, 0);
                    acc[mi][ni] = __builtin_amdgcn_mfma_f32_16x16x32_bf16(al[mi], bh[ni], acc[mi][ni], 0, 0, 0);
                }
        }
    }
    // epilogue: C/D layout col=lane&15, row=(lane>>4)*4+reg
    #pragma unroll
    for (int mi = 0; mi < 2; ++mi)
        #pragma unroll
        for (int ni = 0; ni < 4; ++ni) {
            int col = wn * 64 + ni * 16 + r15;
            float bv = BIAS ? bias[col] : 0.f;
            #pragma unroll
            for (int r = 0; r < 4; ++r) {
                int grow = row0 + wm * 32 + mi * 16 + g * 4 + r;
                if (grow < n) C[(size_t)grow * NCOLS + col] = acc[mi][ni][r] + bv;
            }
        }
}

// ---------------- aggregation: out[i] = dinv[i]*sum_e dinv[s]*hw[s] + dinv[i]^2*hw[i] + b ----------------
template<int COLS, bool RELU>
__global__ __launch_bounds__(256) void agg_kernel(
    const float* __restrict__ hw, const float* __restrict__ dinv,
    const int* __restrict__ rowptr, const int* __restrict__ adj,
    const float* __restrict__ bias, float* __restrict__ out, int n)
{
    const int node = (int)((blockIdx.x * (size_t)blockDim.x + threadIdx.x) >> 6);
    const int lane = threadIdx.x & 63;
    if (node >= n) return;
    const int beg = rowptr[node], end = rowptr[node + 1];
    const float di = dinv[node];

    if (COLS == 128) {
        float acc0 = 0.f, acc1 = 0.f;
        int e = beg;
        for (; e + 1 < end; e += 2) {
            int s0 = adj[e], s1 = adj[e + 1];
            float w0 = dinv[s0], w1 = dinv[s1];
            float2 r0 = *reinterpret_cast<const float2*>(hw + (size_t)s0 * 128 + 2 * lane);
            float2 r1 = *reinterpret_cast<const float2*>(hw + (size_t)s1 * 128 + 2 * lane);
            acc0 += w0 * r0.x; acc1 += w0 * r0.y;
            acc0 += w1 * r1.x; acc1 += w1 * r1.y;
        }
        if (e < end) {
            int s0 = adj[e];
            float w0 = dinv[s0];
            float2 r0 = *reinterpret_cast<const float2*>(hw + (size_t)s0 * 128 + 2 * lane);
            acc0 += w0 * r0.x; acc1 += w0 * r0.y;
        }
        float2 self = *reinterpret_cast<const float2*>(hw + (size_t)node * 128 + 2 * lane);
        float v0 = di * acc0 + di * di * self.x + bias[2 * lane + 0];
        float v1 = di * acc1 + di * di * self.y + bias[2 * lane + 1];
        if (RELU) { v0 = fmaxf(v0, 0.f); v1 = fmaxf(v1, 0.f); }
        *reinterpret_cast<float2*>(out + (size_t)node * 128 + 2 * lane) = make_float2(v0, v1);
    } else {
        float acc0 = 0.f;
        int e = beg;
        for (; e + 1 < end; e += 2) {
            int s0 = adj[e], s1 = adj[e + 1];
            float w0 = dinv[s0], w1 = dinv[s1];
            float r0 = hw[(size_t)s0 * COLS + lane];
            float r1 = hw[(size_t)s1 * COLS + lane];
            acc0 += w0 * r0 + w1 * r1;
        }
        if (e < end) {
            int s0 = adj[e];
            acc0 += dinv[s0] * hw[(size_t)s0 * COLS + lane];
        }
        float self = hw[(size_t)node * COLS + lane];
        float v0 = di * acc0 + di * di * self + bias[lane];
        if (RELU) v0 = fmaxf(v0, 0.f);
        out[(size_t)node * COLS + lane] = v0;
    }
}

// ---------------- launcher ----------------

extern "C" void kernel_launch(void* const* d_in, const int* in_sizes, int n_in,
                              void* d_out, int out_size, void* d_ws, size_t ws_size,
                              hipStream_t stream) {
    const float* x  = (const float*)d_in[0];
    const int*   ei = (const int*)  d_in[1];
    const float* Wu = (const float*)d_in[2];
    const float* bu = (const float*)d_in[3];
    const float* Wb = (const float*)d_in[4];
    const float* bb = (const float*)d_in[5];
    const float* W1 = (const float*)d_in[6];
    const float* b1 = (const float*)d_in[7];
    const float* W2 = (const float*)d_in[8];
    const float* b2 = (const float*)d_in[9];
    const float* W3 = (const float*)d_in[10];
    const float* b3 = (const float*)d_in[11];
    float* out = (float*)d_out;

    const int N_ = in_sizes[0] / FEATC;   // 101024
    const int E_ = in_sizes[1] / 2;       // 2,000,000

    size_t off = 0;
    auto carve = [&](size_t bytes) -> void* {
        void* p = (char*)d_ws + off;
        off += (bytes + 255) & ~(size_t)255;
        return p;
    };
    float*  buf0   = (float*) carve((size_t)N_ * H0 * sizeof(float));
    float*  buf1   = (float*) carve((size_t)N_ * H0 * sizeof(float));
    float*  dinv   = (float*) carve((size_t)N_ * sizeof(float));
    int*    cnt    = (int*)   carve((size_t)N_ * sizeof(int));
    int*    fillc  = (int*)   carve((size_t)N_ * sizeof(int));
    int*    rowptr = (int*)   carve(((size_t)N_ + 1) * sizeof(int));
    int*    adj    = (int*)   carve((size_t)E_ * sizeof(int));
    ushort* wtu_hi = (ushort*)carve((size_t)1024 * 128 * 2);
    ushort* wtu_lo = (ushort*)carve((size_t)1024 * 128 * 2);
    ushort* wtb_hi = (ushort*)carve((size_t)1024 * 128 * 2);
    ushort* wtb_lo = (ushort*)carve((size_t)1024 * 128 * 2);
    ushort* wt1_hi = (ushort*)carve((size_t)128 * 128 * 2);
    ushort* wt1_lo = (ushort*)carve((size_t)128 * 128 * 2);
    ushort* wt2_hi = (ushort*)carve((size_t)128 * 128 * 2);
    ushort* wt2_lo = (ushort*)carve((size_t)128 * 128 * 2);
    ushort* wt3_hi = (ushort*)carve((size_t)128 * 64 * 2);
    ushort* wt3_lo = (ushort*)carve((size_t)128 * 64 * 2);

    // weight packing (transpose + bf16 hi/lo split)
    pack_w_kernel<<<ceil_div(1024 * 128, 256), 256, 0, stream>>>(Wu, wtu_hi, wtu_lo, 1024, 128);
    pack_w_kernel<<<ceil_div(1024 * 128, 256), 256, 0, stream>>>(Wb, wtb_hi, wtb_lo, 1024, 128);
    pack_w_kernel<<<ceil_div(128 * 128, 256), 256, 0, stream>>>(W1, wt1_hi, wt1_lo, 128, 128);
    pack_w_kernel<<<ceil_div(128 * 128, 256), 256, 0, stream>>>(W2, wt2_hi, wt2_lo, 128, 128);
    pack_w_kernel<<<ceil_div(128 * 64, 256), 256, 0, stream>>>(W3, wt3_hi, wt3_lo, 128, 64);

    // CSR + norm build
    init_kernel<<<ceil_div(N_, 256), 256, 0, stream>>>(cnt, fillc, N_);
    count_kernel<<<ceil_div(E_, 256), 256, 0, stream>>>(ei, cnt, E_);
    dinv_kernel<<<ceil_div(N_, 256), 256, 0, stream>>>(cnt, dinv, N_);
    scan_kernel<<<1, 1024, 0, stream>>>(cnt, rowptr, N_);
    fill_kernel<<<ceil_div(E_, 256), 256, 0, stream>>>(ei, rowptr, fillc, adj, E_);

    const int gemm_grid = ceil_div(N_, 128);
    const int agg_grid  = ceil_div(N_, 4);   // 4 waves/block, wave per node

    // h0 = proj(x)  [N,128]
    mfma_gemm_kernel<128, true, true><<<gemm_grid, 512, 0, stream>>>(
        x, 1024, 1024, N_, wtu_hi, wtu_lo, wtb_hi, wtb_lo, bu, bb, buf0);
    // layer 1
    mfma_gemm_kernel<128, false, false><<<gemm_grid, 512, 0, stream>>>(
        buf0, 128, 128, N_, wt1_hi, wt1_lo, wt1_hi, wt1_lo, nullptr, nullptr, buf1);
    agg_kernel<128, true><<<agg_grid, 256, 0, stream>>>(buf1, dinv, rowptr, adj, b1, buf0, N_);
    // layer 2
    mfma_gemm_kernel<128, false, false><<<gemm_grid, 512, 0, stream>>>(
        buf0, 128, 128, N_, wt2_hi, wt2_lo, wt2_hi, wt2_lo, nullptr, nullptr, buf1);
    agg_kernel<128, true><<<agg_grid, 256, 0, stream>>>(buf1, dinv, rowptr, adj, b2, buf0, N_);
    // layer 3 (no relu), write d_out
    mfma_gemm_kernel<64, false, false><<<gemm_grid, 256, 0, stream>>>(
        buf0, 128, 128, N_, wt3_hi, wt3_lo, wt3_hi, wt3_lo, nullptr, nullptr, buf1);
    agg_kernel<64, false><<<agg_grid, 256, 0, stream>>>(buf1, dinv, rowptr, adj, b3, out, N_);
}

// Round 4
// 1289.264 us; speedup vs baseline: 1.2920x; 1.1381x over previous
//
#include <hip/hip_runtime.h>
#include <hip/hip_bf16.h>
#include <stdint.h>

typedef __attribute__((ext_vector_type(8))) short bf16x8;
typedef __attribute__((ext_vector_type(4))) float f32x4;

constexpr int FEATC = 1024;
constexpr int H0 = 128;

static inline int ceil_div(int a, int b){ return (a + b - 1) / b; }

__device__ inline ushort f2bf(float f) {
    __hip_bfloat16 h = __float2bfloat16(f);   // RNE, lowers to v_cvt_pk_bf16_f32 pairs
    union { __hip_bfloat16 h; ushort u; } c;
    c.h = h;
    return c.u;
}
__device__ inline float bf2f(ushort u) { return __uint_as_float(((uint)u) << 16); }
__device__ inline uint pack2(ushort a, ushort b) { return (uint)a | ((uint)b << 16); }

// ---------------- CSR build ----------------

__global__ __launch_bounds__(256) void init_kernel(int* __restrict__ cnt, int* __restrict__ fill, int n) {
    int i = blockIdx.x * 256 + threadIdx.x;
    if (i < n) { cnt[i] = 0; fill[i] = 0; }
}

__global__ __launch_bounds__(256) void count_kernel(const int* __restrict__ ei, int* __restrict__ cnt, int E) {
    int e = blockIdx.x * 256 + threadIdx.x;
    if (e < E) atomicAdd(&cnt[ei[E + e]], 1);   // dst row
}

__global__ __launch_bounds__(256) void dinv_kernel(const int* __restrict__ cnt, float* __restrict__ dinv, int n) {
    int i = blockIdx.x * 256 + threadIdx.x;
    if (i < n) dinv[i] = rsqrtf((float)(cnt[i] + 1));   // +1 self loop
}

// ---- 3-pass exclusive scan: cnt[0..n) -> rowptr[0..n] ----
__global__ __launch_bounds__(256) void scan_a_kernel(const int* __restrict__ cnt, int* __restrict__ rowptr,
                                                     int* __restrict__ bsum, int n) {
    __shared__ int wsum_[4];
    const int tid = threadIdx.x, lane = tid & 63, wid = tid >> 6;
    const int base = blockIdx.x * 1024 + tid * 4;
    int4 v = make_int4(0, 0, 0, 0);
    if (base + 3 < n) v = *reinterpret_cast<const int4*>(cnt + base);
    else {
        if (base     < n) v.x = cnt[base];
        if (base + 1 < n) v.y = cnt[base + 1];
        if (base + 2 < n) v.z = cnt[base + 2];
        if (base + 3 < n) v.w = cnt[base + 3];
    }
    const int tsum = v.x + v.y + v.z + v.w;
    int s = tsum;
    #pragma unroll
    for (int off = 1; off < 64; off <<= 1) { int t = __shfl_up(s, off, 64); if (lane >= off) s += t; }
    if (lane == 63) wsum_[wid] = s;
    __syncthreads();
    const int woff = (wid > 0 ? wsum_[0] : 0) + (wid > 1 ? wsum_[1] : 0) + (wid > 2 ? wsum_[2] : 0);
    const int excl = woff + s - tsum;
    if (base     < n) rowptr[base]     = excl;
    if (base + 1 < n) rowptr[base + 1] = excl + v.x;
    if (base + 2 < n) rowptr[base + 2] = excl + v.x + v.y;
    if (base + 3 < n) rowptr[base + 3] = excl + v.x + v.y + v.z;
    if (tid == 255) bsum[blockIdx.x] = woff + s;
}

__global__ __launch_bounds__(256) void scan_b_kernel(int* __restrict__ bsum, int* __restrict__ rowptr, int n, int B) {
    __shared__ int wsum_[4];
    const int tid = threadIdx.x, lane = tid & 63, wid = tid >> 6;
    const int v = (tid < B) ? bsum[tid] : 0;
    int s = v;
    #pragma unroll
    for (int off = 1; off < 64; off <<= 1) { int t = __shfl_up(s, off, 64); if (lane >= off) s += t; }
    if (lane == 63) wsum_[wid] = s;
    __syncthreads();
    const int woff = (wid > 0 ? wsum_[0] : 0) + (wid > 1 ? wsum_[1] : 0) + (wid > 2 ? wsum_[2] : 0);
    const int excl = woff + s - v;
    if (tid < B) bsum[tid] = excl;
    if (tid == 255) rowptr[n] = woff + s;   // grand total
}

__global__ __launch_bounds__(256) void scan_c_kernel(int* __restrict__ rowptr, const int* __restrict__ bsum, int n) {
    const int add = bsum[blockIdx.x];
    const int base = blockIdx.x * 1024 + threadIdx.x * 4;
    if (base + 3 < n) {
        int4 t = *reinterpret_cast<int4*>(rowptr + base);
        t.x += add; t.y += add; t.z += add; t.w += add;
        *reinterpret_cast<int4*>(rowptr + base) = t;
    } else {
        #pragma unroll
        for (int k = 0; k < 4; ++k) if (base + k < n) rowptr[base + k] += add;
    }
}

__global__ __launch_bounds__(256) void fill_kernel(const int* __restrict__ ei, const int* __restrict__ rowptr,
                                                   int* __restrict__ fill, int* __restrict__ adj, int E) {
    int e = blockIdx.x * 256 + threadIdx.x;
    if (e < E) {
        int d = ei[E + e];
        int pos = rowptr[d] + atomicAdd(&fill[d], 1);
        adj[pos] = ei[e];
    }
}

// ---------------- weight pack: W [K][N] fp32 -> Wt_hi/Wt_lo [N][K] bf16 ----------------
__global__ __launch_bounds__(256) void pack_w_kernel(const float* __restrict__ W, ushort* __restrict__ hi,
                                                     ushort* __restrict__ lo, int K, int N) {
    int o = blockIdx.x * 256 + threadIdx.x;
    if (o >= K * N) return;
    int nn = o / K, kk = o - nn * K;
    float f = W[(size_t)kk * N + nn];
    ushort h = f2bf(f);
    hi[o] = h;
    lo[o] = f2bf(f - bf2f(h));
}

// ---------------- bf16x3-split MFMA GEMM ----------------
// C[n][NCOLS] = A[n][K] @ W[K][NCOLS]; BM=128, BK=64; waves 4(m) x NCOLS/64(n).
// A either fp32 (converted in-kernel, proj) or pre-split bf16 hi/lo arrays (layers).
// Epilogue: optional bias, optional dinv row-scale, output fp32 or bf16 hi/lo.
template<int NCOLS, bool SPLIT, bool A_F32, bool BIAS, bool OUT_BF16, bool DINV>
__global__ __launch_bounds__(NCOLS == 128 ? 512 : 256) void mfma_gemm_kernel(
    const float* __restrict__ Af, const ushort* __restrict__ AhiG, const ushort* __restrict__ AloG,
    int lda, int K, int n,
    const ushort* __restrict__ WtHiA, const ushort* __restrict__ WtLoA,
    const ushort* __restrict__ WtHiB, const ushort* __restrict__ WtLoB,
    const float* __restrict__ biasA, const float* __restrict__ biasB,
    const float* __restrict__ dinv,
    float* __restrict__ Cf, ushort* __restrict__ Chi, ushort* __restrict__ Clo)
{
    constexpr int BM = 128, BK = 64;
    constexpr int WN = NCOLS / 64;
    constexpr int THREADS = 4 * WN * 64;                 // 512 or 256
    __shared__ alignas(16) ushort Ahi[BM * BK], Alo[BM * BK];
    __shared__ alignas(16) ushort Bhi[NCOLS * BK], Blo[NCOLS * BK];

    const int tid = threadIdx.x;
    const int row0 = blockIdx.x * BM;
    const ushort* WtHi = (SPLIT && row0 >= 1024) ? WtHiB : WtHiA;
    const ushort* WtLo = (SPLIT && row0 >= 1024) ? WtLoB : WtLoA;
    const float*  bias = (SPLIT && row0 >= 1024) ? biasB : biasA;

    const int wave = tid >> 6, lane = tid & 63;
    const int wn = wave % WN, wm = wave / WN;
    const int r15 = lane & 15, g = lane >> 4;

    f32x4 acc[2][4];
    #pragma unroll
    for (int i = 0; i < 2; ++i)
        #pragma unroll
        for (int j = 0; j < 4; ++j) acc[i][j] = (f32x4){0.f, 0.f, 0.f, 0.f};

    for (int k0 = 0; k0 < K; k0 += BK) {
        __syncthreads();
        if constexpr (A_F32) {
            constexpr int ASTEPS = (BM * BK / 4) / THREADS;   // 4
            #pragma unroll
            for (int ii = 0; ii < ASTEPS; ++ii) {
                int chunk = tid + ii * THREADS;
                int r = chunk >> 4, c = chunk & 15;
                int grow = row0 + r;
                float4 v = make_float4(0.f, 0.f, 0.f, 0.f);
                if (grow < n) v = *reinterpret_cast<const float4*>(Af + (size_t)grow * lda + k0 + c * 4);
                ushort h0 = f2bf(v.x), h1 = f2bf(v.y), h2 = f2bf(v.z), h3 = f2bf(v.w);
                float l0 = v.x - bf2f(h0), l1 = v.y - bf2f(h1);
                float l2 = v.z - bf2f(h2), l3 = v.w - bf2f(h3);
                uint2 hu = make_uint2(pack2(h0, h1), pack2(h2, h3));
                uint2 lu = make_uint2(pack2(f2bf(l0), f2bf(l1)), pack2(f2bf(l2), f2bf(l3)));
                int bo = r * 128 + c * 8;
                int sw = bo ^ (((bo >> 7) & 7) << 4);
                *reinterpret_cast<uint2*>((char*)Ahi + sw) = hu;
                *reinterpret_cast<uint2*>((char*)Alo + sw) = lu;
            }
        } else {
            constexpr int ASTEPS = (BM * BK / 8) / THREADS;   // 2 or 4
            #pragma unroll
            for (int ii = 0; ii < ASTEPS; ++ii) {
                int chunk = tid + ii * THREADS;
                int r = chunk >> 3, c = chunk & 7;
                int grow = row0 + r;
                bf16x8 hv{}, lv{};
                if (grow < n) {
                    hv = *reinterpret_cast<const bf16x8*>(AhiG + (size_t)grow * lda + k0 + c * 8);
                    lv = *reinterpret_cast<const bf16x8*>(AloG + (size_t)grow * lda + k0 + c * 8);
                }
                int bo = r * 128 + c * 16;
                int sw = bo ^ (((bo >> 7) & 7) << 4);
                *reinterpret_cast<bf16x8*>((char*)Ahi + sw) = hv;
                *reinterpret_cast<bf16x8*>((char*)Alo + sw) = lv;
            }
        }
        {
            constexpr int BSTEPS = (NCOLS * BK / 8) / THREADS;  // 2
            #pragma unroll
            for (int ii = 0; ii < BSTEPS; ++ii) {
                int chunk = tid + ii * THREADS;
                int r = chunk >> 3, c = chunk & 7;
                bf16x8 hv = *reinterpret_cast<const bf16x8*>(WtHi + (size_t)r * K + k0 + c * 8);
                bf16x8 lv = *reinterpret_cast<const bf16x8*>(WtLo + (size_t)r * K + k0 + c * 8);
                int bo = r * 128 + c * 16;
                int sw = bo ^ (((bo >> 7) & 7) << 4);
                *reinterpret_cast<bf16x8*>((char*)Bhi + sw) = hv;
                *reinterpret_cast<bf16x8*>((char*)Blo + sw) = lv;
            }
        }
        __syncthreads();
        #pragma unroll
        for (int ks = 0; ks < 2; ++ks) {
            bf16x8 ah[2], al[2], bh[4], bl[4];
            #pragma unroll
            for (int mi = 0; mi < 2; ++mi) {
                int row = wm * 32 + mi * 16 + r15;
                int bo = row * 128 + ks * 64 + g * 16;
                int sw = bo ^ (((bo >> 7) & 7) << 4);
                ah[mi] = *reinterpret_cast<const bf16x8*>((const char*)Ahi + sw);
                al[mi] = *reinterpret_cast<const bf16x8*>((const char*)Alo + sw);
            }
            #pragma unroll
            for (int ni = 0; ni < 4; ++ni) {
                int row = wn * 64 + ni * 16 + r15;
                int bo = row * 128 + ks * 64 + g * 16;
                int sw = bo ^ (((bo >> 7) & 7) << 4);
                bh[ni] = *reinterpret_cast<const bf16x8*>((const char*)Bhi + sw);
                bl[ni] = *reinterpret_cast<const bf16x8*>((const char*)Blo + sw);
            }
            #pragma unroll
            for (int mi = 0; mi < 2; ++mi)
                #pragma unroll
                for (int ni = 0; ni < 4; ++ni) {
                    acc[mi][ni] = __builtin_amdgcn_mfma_f32_16x16x32_bf16(ah[mi], bh[ni], acc[mi][ni], 0, 0, 0);
                    acc[mi][ni] = __builtin_amdgcn_mfma_f32_16x16x32_bf16(ah[mi], bl[ni], acc[mi][ni], 0, 0, 0);
                    acc[mi][ni] = __builtin_amdgcn_mfma_f32_16x16x32_bf16(al[mi], bh[ni], acc[mi][ni], 0, 0, 0);
                }
        }
    }
    // epilogue: C/D layout col=lane&15, row=(lane>>4)*4+reg
    #pragma unroll
    for (int mi = 0; mi < 2; ++mi)
        #pragma unroll
        for (int ni = 0; ni < 4; ++ni) {
            int col = wn * 64 + ni * 16 + r15;
            float bv = BIAS ? bias[col] : 0.f;
            #pragma unroll
            for (int r = 0; r < 4; ++r) {
                int grow = row0 + wm * 32 + mi * 16 + g * 4 + r;
                if (grow < n) {
                    float v = acc[mi][ni][r] + bv;
                    if (DINV) v *= dinv[grow];
                    if (OUT_BF16) {
                        ushort h = f2bf(v);
                        Chi[(size_t)grow * NCOLS + col] = h;
                        Clo[(size_t)grow * NCOLS + col] = f2bf(v - bf2f(h));
                    } else {
                        Cf[(size_t)grow * NCOLS + col] = v;
                    }
                }
            }
        }
}

// ---------------- aggregation ----------------
// hw' rows already scaled by dinv[src]; out[i] = dinv[i]*(sum_e hw'[s] + hw'[i]) + b
template<int COLS, bool RELU, bool OUT_BF16>
__global__ __launch_bounds__(256) void agg_kernel(
    const float* __restrict__ hw, const float* __restrict__ dinv,
    const int* __restrict__ rowptr, const int* __restrict__ adj,
    const float* __restrict__ bias, float* __restrict__ outF,
    ushort* __restrict__ outHi, ushort* __restrict__ outLo, int n)
{
    const int node = (int)((blockIdx.x * (size_t)blockDim.x + threadIdx.x) >> 6);
    const int lane = threadIdx.x & 63;
    if (node >= n) return;
    const int beg = rowptr[node], end = rowptr[node + 1];
    const float di = dinv[node];

    if (COLS == 128) {
        float2 self = *reinterpret_cast<const float2*>(hw + (size_t)node * 128 + 2 * lane);
        float acc0 = self.x, acc1 = self.y;
        int e = beg;
        for (; e + 3 < end; e += 4) {
            int s0 = adj[e], s1 = adj[e + 1], s2 = adj[e + 2], s3 = adj[e + 3];
            float2 r0 = *reinterpret_cast<const float2*>(hw + (size_t)s0 * 128 + 2 * lane);
            float2 r1 = *reinterpret_cast<const float2*>(hw + (size_t)s1 * 128 + 2 * lane);
            float2 r2 = *reinterpret_cast<const float2*>(hw + (size_t)s2 * 128 + 2 * lane);
            float2 r3 = *reinterpret_cast<const float2*>(hw + (size_t)s3 * 128 + 2 * lane);
            acc0 += r0.x + r1.x + r2.x + r3.x;
            acc1 += r0.y + r1.y + r2.y + r3.y;
        }
        for (; e < end; ++e) {
            int s0 = adj[e];
            float2 r0 = *reinterpret_cast<const float2*>(hw + (size_t)s0 * 128 + 2 * lane);
            acc0 += r0.x; acc1 += r0.y;
        }
        float2 bv = *reinterpret_cast<const float2*>(bias + 2 * lane);
        float v0 = di * acc0 + bv.x;
        float v1 = di * acc1 + bv.y;
        if (RELU) { v0 = fmaxf(v0, 0.f); v1 = fmaxf(v1, 0.f); }
        if (OUT_BF16) {
            ushort h0 = f2bf(v0), h1 = f2bf(v1);
            *reinterpret_cast<uint*>(outHi + (size_t)node * 128 + 2 * lane) = pack2(h0, h1);
            *reinterpret_cast<uint*>(outLo + (size_t)node * 128 + 2 * lane) =
                pack2(f2bf(v0 - bf2f(h0)), f2bf(v1 - bf2f(h1)));
        } else {
            *reinterpret_cast<float2*>(outF + (size_t)node * 128 + 2 * lane) = make_float2(v0, v1);
        }
    } else {
        float acc0 = hw[(size_t)node * COLS + lane];
        int e = beg;
        for (; e + 3 < end; e += 4) {
            int s0 = adj[e], s1 = adj[e + 1], s2 = adj[e + 2], s3 = adj[e + 3];
            float r0 = hw[(size_t)s0 * COLS + lane];
            float r1 = hw[(size_t)s1 * COLS + lane];
            float r2 = hw[(size_t)s2 * COLS + lane];
            float r3 = hw[(size_t)s3 * COLS + lane];
            acc0 += r0 + r1 + r2 + r3;
        }
        for (; e < end; ++e) acc0 += hw[(size_t)adj[e] * COLS + lane];
        float v0 = di * acc0 + bias[lane];
        if (RELU) v0 = fmaxf(v0, 0.f);
        outF[(size_t)node * COLS + lane] = v0;
    }
}

// ---------------- launcher ----------------

extern "C" void kernel_launch(void* const* d_in, const int* in_sizes, int n_in,
                              void* d_out, int out_size, void* d_ws, size_t ws_size,
                              hipStream_t stream) {
    const float* x  = (const float*)d_in[0];
    const int*   ei = (const int*)  d_in[1];
    const float* Wu = (const float*)d_in[2];
    const float* bu = (const float*)d_in[3];
    const float* Wb = (const float*)d_in[4];
    const float* bb = (const float*)d_in[5];
    const float* W1 = (const float*)d_in[6];
    const float* b1 = (const float*)d_in[7];
    const float* W2 = (const float*)d_in[8];
    const float* b2 = (const float*)d_in[9];
    const float* W3 = (const float*)d_in[10];
    const float* b3 = (const float*)d_in[11];
    float* out = (float*)d_out;

    const int N_ = in_sizes[0] / FEATC;   // 101024
    const int E_ = in_sizes[1] / 2;       // 2,000,000
    const int SB = ceil_div(N_, 1024);    // scan blocks (99)

    size_t off = 0;
    auto carve = [&](size_t bytes) -> void* {
        void* p = (char*)d_ws + off;
        off += (bytes + 255) & ~(size_t)255;
        return p;
    };
    float*  bufF   = (float*) carve((size_t)N_ * H0 * sizeof(float));   // GEMM outputs (hw')
    ushort* hHi    = (ushort*)carve((size_t)N_ * H0 * 2);               // activations bf16 hi
    ushort* hLo    = (ushort*)carve((size_t)N_ * H0 * 2);               // activations bf16 lo
    float*  dinv   = (float*) carve((size_t)N_ * sizeof(float));
    int*    cnt    = (int*)   carve((size_t)N_ * sizeof(int));
    int*    fillc  = (int*)   carve((size_t)N_ * sizeof(int));
    int*    rowptr = (int*)   carve(((size_t)N_ + 1) * sizeof(int));
    int*    bsum   = (int*)   carve(256 * sizeof(int));
    int*    adj    = (int*)   carve((size_t)E_ * sizeof(int));
    ushort* wtu_hi = (ushort*)carve((size_t)1024 * 128 * 2);
    ushort* wtu_lo = (ushort*)carve((size_t)1024 * 128 * 2);
    ushort* wtb_hi = (ushort*)carve((size_t)1024 * 128 * 2);
    ushort* wtb_lo = (ushort*)carve((size_t)1024 * 128 * 2);
    ushort* wt1_hi = (ushort*)carve((size_t)128 * 128 * 2);
    ushort* wt1_lo = (ushort*)carve((size_t)128 * 128 * 2);
    ushort* wt2_hi = (ushort*)carve((size_t)128 * 128 * 2);
    ushort* wt2_lo = (ushort*)carve((size_t)128 * 128 * 2);
    ushort* wt3_hi = (ushort*)carve((size_t)128 * 64 * 2);
    ushort* wt3_lo = (ushort*)carve((size_t)128 * 64 * 2);

    // weight packing (transpose + bf16 hi/lo split)
    pack_w_kernel<<<ceil_div(1024 * 128, 256), 256, 0, stream>>>(Wu, wtu_hi, wtu_lo, 1024, 128);
    pack_w_kernel<<<ceil_div(1024 * 128, 256), 256, 0, stream>>>(Wb, wtb_hi, wtb_lo, 1024, 128);
    pack_w_kernel<<<ceil_div(128 * 128, 256), 256, 0, stream>>>(W1, wt1_hi, wt1_lo, 128, 128);
    pack_w_kernel<<<ceil_div(128 * 128, 256), 256, 0, stream>>>(W2, wt2_hi, wt2_lo, 128, 128);
    pack_w_kernel<<<ceil_div(128 * 64, 256), 256, 0, stream>>>(W3, wt3_hi, wt3_lo, 128, 64);

    // CSR + norm build
    init_kernel<<<ceil_div(N_, 256), 256, 0, stream>>>(cnt, fillc, N_);
    count_kernel<<<ceil_div(E_, 256), 256, 0, stream>>>(ei, cnt, E_);
    dinv_kernel<<<ceil_div(N_, 256), 256, 0, stream>>>(cnt, dinv, N_);
    scan_a_kernel<<<SB, 256, 0, stream>>>(cnt, rowptr, bsum, N_);
    scan_b_kernel<<<1, 256, 0, stream>>>(bsum, rowptr, N_, SB);
    scan_c_kernel<<<SB, 256, 0, stream>>>(rowptr, bsum, N_);
    fill_kernel<<<ceil_div(E_, 256), 256, 0, stream>>>(ei, rowptr, fillc, adj, E_);

    const int gemm_grid = ceil_div(N_, 128);
    const int agg_grid  = ceil_div(N_, 4);   // 4 waves/block, wave per node

    // proj: h = x@Wu/Wb + b  -> bf16 hi/lo
    mfma_gemm_kernel<128, true, true, true, true, false><<<gemm_grid, 512, 0, stream>>>(
        x, nullptr, nullptr, 1024, 1024, N_,
        wtu_hi, wtu_lo, wtb_hi, wtb_lo, bu, bb, nullptr, nullptr, hHi, hLo);
    // layer 1: hw' = dinv * (h@W1) -> fp32; agg -> bf16 hi/lo
    mfma_gemm_kernel<128, false, false, false, false, true><<<gemm_grid, 512, 0, stream>>>(
        nullptr, hHi, hLo, 128, 128, N_,
        wt1_hi, wt1_lo, wt1_hi, wt1_lo, nullptr, nullptr, dinv, bufF, nullptr, nullptr);
    agg_kernel<128, true, true><<<agg_grid, 256, 0, stream>>>(
        bufF, dinv, rowptr, adj, b1, nullptr, hHi, hLo, N_);
    // layer 2
    mfma_gemm_kernel<128, false, false, false, false, true><<<gemm_grid, 512, 0, stream>>>(
        nullptr, hHi, hLo, 128, 128, N_,
        wt2_hi, wt2_lo, wt2_hi, wt2_lo, nullptr, nullptr, dinv, bufF, nullptr, nullptr);
    agg_kernel<128, true, true><<<agg_grid, 256, 0, stream>>>(
        bufF, dinv, rowptr, adj, b2, nullptr, hHi, hLo, N_);
    // layer 3 (no relu) -> d_out fp32
    mfma_gemm_kernel<64, false, false, false, false, true><<<gemm_grid, 256, 0, stream>>>(
        nullptr, hHi, hLo, 128, 128, N_,
        wt3_hi, wt3_lo, wt3_hi, wt3_lo, nullptr, nullptr, dinv, bufF, nullptr, nullptr);
    agg_kernel<64, false, false><<<agg_grid, 256, 0, stream>>>(
        bufF, dinv, rowptr, adj, b3, out, nullptr, nullptr, N_);
}